// Round 14
// baseline (3659.726 us; speedup 1.0000x reference)
//
#include <hip/hip_runtime.h>
#include <hip/hip_bf16.h>

// BasicLSTM: B=64, T=512, D=512, U=1024.  out = h_last [64][1024] f32.
// Round 14 = R9 (proven best) with k_xproj FUSED into the recurrence:
// xz(s+1) for the block's 16 rows x 128 z-cols is computed between
// flag-publish and poll -- inside the ~2us window where the block would
// idle waiting for peers' h to reach L3. One-step LDS ring xzb[2].
// No xz workspace, no chunking: ONE persistent k_lstm, c in registers
// for all 512 steps. Stage/MFMA/gates/barrier byte-identical to R9.

#define T_STEPS 512
#define BATCH   64
#define DIM     512
#define UNITS   1024
#define ZCOLS   4096
#define MR      16     // rows per m-group

typedef float        f32x4 __attribute__((ext_vector_type(4)));
typedef unsigned int u32x4 __attribute__((ext_vector_type(4)));

__device__ __forceinline__ f32x4 mfma16x16x32_bf16(u32x4 a, u32x4 b, f32x4 c) {
    asm("v_mfma_f32_16x16x32_bf16 %0, %1, %2, %0" : "+v"(c) : "v"(a), "v"(b));
    return c;
}

__device__ __forceinline__ unsigned short f2bf(float f) {
    union { float f; unsigned u; } v; v.f = f;
    unsigned r = v.u + 0x7fffu + ((v.u >> 16) & 1u);   // RNE
    return (unsigned short)(r >> 16);
}

__device__ __forceinline__ float fsigmoid(float x) { return 1.0f / (1.0f + __expf(-x)); }
__device__ __forceinline__ float ftanh(float x)    { return 1.0f - 2.0f / (__expf(2.0f * x) + 1.0f); }

__device__ __forceinline__ u32x4 pack8(const float* __restrict__ p) {
    float4 f0 = reinterpret_cast<const float4*>(p)[0];
    float4 f1 = reinterpret_cast<const float4*>(p)[1];
    u32x4 r;
    r.x = (unsigned)f2bf(f0.x) | ((unsigned)f2bf(f0.y) << 16);
    r.y = (unsigned)f2bf(f0.z) | ((unsigned)f2bf(f0.w) << 16);
    r.z = (unsigned)f2bf(f1.x) | ((unsigned)f2bf(f1.y) << 16);
    r.w = (unsigned)f2bf(f1.z) | ((unsigned)f2bf(f1.w) << 16);
    return r;
}

#define LD4(d, base) \
    asm volatile("global_load_dwordx4 %0, %1, off sc0 sc1" : "=v"(d) : "v"(base));
#define WAITV0 \
    asm volatile("s_waitcnt vmcnt(0)" ::: "memory"); \
    __builtin_amdgcn_sched_barrier(0);

// ---------------- prep kernels ----------------

__global__ void k_transpose_bf16(const float* __restrict__ in, unsigned short* __restrict__ out,
                                 int K, int N) {
    __shared__ float tile[32][33];
    int n0 = blockIdx.x * 32, k0 = blockIdx.y * 32;
    int tx = threadIdx.x, ty = threadIdx.y;
    tile[ty][tx] = in[(size_t)(k0 + ty) * N + n0 + tx];
    __syncthreads();
    out[(size_t)(n0 + ty) * K + k0 + tx] = f2bf(tile[tx][ty]);
}

__global__ void k_init(unsigned int* __restrict__ hbuf_u32, unsigned int* __restrict__ flags) {
    int i = blockIdx.x * blockDim.x + threadIdx.x;       // >= 69632 threads
    if (i < 65536) hbuf_u32[i] = 0u;                     // 2*64*1024 bf16
    else if (i < 65536 + 4096) flags[i - 65536] = 0u;    // 128 flags * 32 u32
}

// ---------------- fused persistent recurrence ----------------
// 128 blocks x 512 thr. Block (mg = bid>>5, zb = bid&31): rows [16mg,+16),
// units [32zb,+32) x 4 gates. Waves: ct=w&3 (gate), kh=w>>2 (K half) for
// the h@Wh phase; wave w = n-tile (g=w>>1, uh=w&1) for the xz phase.
__global__ __launch_bounds__(512, 1) void k_lstm(
        const float* __restrict__ x,             // [64][512][512] f32
        const unsigned short* __restrict__ WxT,  // [4096][512] bf16
        const unsigned short* __restrict__ WhT,  // [4096][1024] bf16
        const float* __restrict__ bias,          // [4096] f32
        unsigned short* hbuf,                    // [2][64][1024] bf16
        float* __restrict__ out,                 // [64][1024] f32
        unsigned int* flags) {                   // [128] spaced 32 u32
    const int tid  = threadIdx.x;
    const int lane = tid & 63;
    const int w    = tid >> 6;          // 0..7
    const int ct   = w & 3;             // gate (h@Wh phase)
    const int kh   = w >> 2;            // K half (h@Wh phase)
    const int mg   = blockIdx.x >> 5;   // m-group 0..3
    const int zb   = blockIdx.x & 31;   // z-block 0..31
    const int r0   = mg * MR;
    const int u0   = zb * 32;
    const int c16  = lane & 15;
    const int kl   = (lane >> 4) * 8;   // k elem offset (32-elem step)
    const int klb  = (lane >> 4) * 16;  // k byte offset within 64B kk-chunk

    __shared__ __align__(16) unsigned short hs[MR * 1024];   // 32 KB, swizzled
    __shared__ float zbuf[2][MR][132];                       // 16.9 KB
    __shared__ __align__(16) unsigned short xs[MR * 512];    // 16 KB, swizzled
    __shared__ float xzb[2][MR][132];                        // 16.9 KB

    // Wh slice in VGPRs (R9 exact): breg[n][kk] = WhT row ct*1024+u0+n*16+c16
    u32x4 breg[2][16];
    #pragma unroll
    for (int n = 0; n < 2; ++n) {
        const unsigned short* wp =
            WhT + ((size_t)(ct * UNITS + u0 + n * 16 + c16)) * UNITS + kh * 512 + kl;
        #pragma unroll
        for (int kk = 0; kk < 16; ++kk) {
            breg[n][kk] = *reinterpret_cast<const u32x4*>(wp + kk * 32);
            asm volatile("" : "+v"(breg[n][kk]));
        }
    }

    // gate identity: one (row, unit) per thread; c lives in a register all run
    const int ri = tid >> 5;            // 0..15
    const int ui = tid & 31;            // 0..31
    float creg = 0.0f;
    float bi0 = bias[u0 + ui];
    float bi1 = bias[UNITS + u0 + ui];
    float bi2 = bias[2 * UNITS + u0 + ui];
    float bi3 = bias[3 * UNITS + u0 + ui];

    unsigned int* const myflag = flags + (size_t)blockIdx.x * 32;
    const unsigned int* const gflags = flags + (size_t)mg * 32 * 32;

    // xz B pointer for this wave's n-tile: WxT row (w>>1)*1024 + u0 + (w&1)*16 + c16
    const unsigned short* const bpx =
        WxT + ((size_t)((w >> 1) * UNITS + u0 + (w & 1) * 16 + c16)) * DIM + kl;

    // ---- xz compute helper phases (macro-free, inlined twice) ----
    // stage_x(st): 16 rows of x[.,st,:] f32 -> packed bf16 swizzled xs
    // xz_mfma(par): per-wave 16x16 n-tile, K=512 -> xzb[par]

    // prologue: xz(0) into xzb[0]
    {
        #pragma unroll
        for (int j = 0; j < 2; ++j) {
            int i = tid + j * 512;          // 0..1023
            int row = i >> 6, kc8 = i & 63;
            u32x4 v = pack8(x + ((size_t)(r0 + row) * T_STEPS + 0) * DIM + kc8 * 8);
            int lb = (row * 1024 + kc8 * 16) ^ ((row & 7) << 4);
            *reinterpret_cast<u32x4*>(reinterpret_cast<char*>(xs) + lb) = v;
        }
        __syncthreads();
        f32x4 xacc = {0, 0, 0, 0};
        asm volatile("s_nop 1" : "+v"(xacc));
        #pragma unroll
        for (int kk = 0; kk < 16; ++kk) {
            u32x4 b = *reinterpret_cast<const u32x4*>(bpx + kk * 32);
            int lb = (c16 * 1024 + (kk * 32 + kl) * 2) ^ ((c16 & 7) << 4);
            u32x4 a = *reinterpret_cast<const u32x4*>(reinterpret_cast<const char*>(xs) + lb);
            xacc = mfma16x16x32_bf16(a, b, xacc);
        }
        asm volatile("s_nop 7\n\ts_nop 7" : "+v"(xacc));
        const int rowq = (lane >> 4) * 4;
        #pragma unroll
        for (int r = 0; r < 4; ++r)
            xzb[0][rowq + r][w * 16 + c16] = xacc[r];
        __syncthreads();
    }

    for (int s = 0; s < T_STEPS; ++s) {
        const unsigned short* hrd = hbuf + (size_t)(s & 1) * (BATCH * UNITS);

        // --- stage group h(s) -> swizzled LDS (R9 exact) ---
        {
            u32x4 sv[4];
            #pragma unroll
            for (int j = 0; j < 4; ++j) {
                int i = tid + j * 512;          // 16B-chunk index 0..2047
                int row = i >> 7, kc = i & 127;
                const unsigned short* src = hrd + (size_t)(r0 + row) * UNITS + kc * 8;
                LD4(sv[j], src)
            }
            WAITV0
            #pragma unroll
            for (int j = 0; j < 4; ++j) {
                int i = tid + j * 512;
                int row = i >> 7, kc = i & 127;
                int lb = (row * 2048 + kc * 16) ^ ((row & 7) << 4);
                *reinterpret_cast<u32x4*>(reinterpret_cast<char*>(hs) + lb) = sv[j];
            }
        }
        __syncthreads();

        // --- h @ Wh MFMA (R9 exact) ---
        f32x4 acc0 = {0, 0, 0, 0}, acc1 = {0, 0, 0, 0};
        asm volatile("s_nop 1" : "+v"(acc0), "+v"(acc1));
        const char* abase = reinterpret_cast<const char*>(hs);
        const int axor = (c16 & 7) << 4;
        #pragma unroll
        for (int kk = 0; kk < 16; ++kk) {
            int lb = (c16 * 2048 + kh * 1024 + kk * 64 + klb) ^ axor;
            u32x4 a = *reinterpret_cast<const u32x4*>(abase + lb);
            acc0 = mfma16x16x32_bf16(a, breg[0][kk], acc0);
            acc1 = mfma16x16x32_bf16(a, breg[1][kk], acc1);
        }
        asm volatile("s_nop 7\n\ts_nop 7" : "+v"(acc0), "+v"(acc1));
        {
            const int rowq = (lane >> 4) * 4;
            #pragma unroll
            for (int r = 0; r < 4; ++r) {
                zbuf[kh][rowq + r][ct * 32 + c16]      = acc0[r];
                zbuf[kh][rowq + r][ct * 32 + 16 + c16] = acc1[r];
            }
        }
        __syncthreads();

        // --- gates: all 512 threads, one (ri, ui) each ---
        {
            const float* xzr = xzb[s & 1][ri];
            float zi = zbuf[0][ri][ui]      + zbuf[1][ri][ui]      + xzr[ui]      + bi0;
            float zf = zbuf[0][ri][32 + ui] + zbuf[1][ri][32 + ui] + xzr[32 + ui] + bi1;
            float zg = zbuf[0][ri][64 + ui] + zbuf[1][ri][64 + ui] + xzr[64 + ui] + bi2;
            float zo = zbuf[0][ri][96 + ui] + zbuf[1][ri][96 + ui] + xzr[96 + ui] + bi3;
            float ig = fsigmoid(zi), fg = fsigmoid(zf), gg = ftanh(zg), og = fsigmoid(zo);
            creg = fg * creg + ig * gg;
            float hn = og * ftanh(creg);
            unsigned hv = f2bf(hn);
            unsigned short* hwp = hbuf + (size_t)((s + 1) & 1) * (BATCH * UNITS)
                                  + (size_t)(r0 + ri) * UNITS + u0 + ui;
            asm volatile("global_store_short %0, %1, off sc0 sc1" :: "v"(hwp), "v"(hv) : "memory");
            if (s == T_STEPS - 1) out[(size_t)(r0 + ri) * UNITS + u0 + ui] = hn;
        }

        if (s < T_STEPS - 1) {
            // --- publish (R9 exact) ---
            WAITV0                              // own h stores acked (L3)
            __syncthreads();                    // whole block drained
            if (tid == 0) {
                unsigned fv = (unsigned)(s + 1);
                asm volatile("global_store_dword %0, %1, off sc0 sc1"
                             :: "v"(myflag), "v"(fv) : "memory");
                asm volatile("s_waitcnt vmcnt(0)" ::: "memory");
            }

            // --- fused xz(s+1): fills the flag-propagation window ---
            {
                #pragma unroll
                for (int j = 0; j < 2; ++j) {
                    int i = tid + j * 512;
                    int row = i >> 6, kc8 = i & 63;
                    u32x4 v = pack8(x + ((size_t)(r0 + row) * T_STEPS + (s + 1)) * DIM + kc8 * 8);
                    int lb = (row * 1024 + kc8 * 16) ^ ((row & 7) << 4);
                    *reinterpret_cast<u32x4*>(reinterpret_cast<char*>(xs) + lb) = v;
                }
                __syncthreads();
                f32x4 xacc = {0, 0, 0, 0};
                asm volatile("s_nop 1" : "+v"(xacc));
                #pragma unroll
                for (int kk = 0; kk < 16; ++kk) {
                    u32x4 b = *reinterpret_cast<const u32x4*>(bpx + kk * 32);
                    int lb = (c16 * 1024 + (kk * 32 + kl) * 2) ^ ((c16 & 7) << 4);
                    u32x4 a = *reinterpret_cast<const u32x4*>(reinterpret_cast<const char*>(xs) + lb);
                    xacc = mfma16x16x32_bf16(a, b, xacc);
                }
                asm volatile("s_nop 7\n\ts_nop 7" : "+v"(xacc));
                const int rowq = (lane >> 4) * 4;
                #pragma unroll
                for (int r = 0; r < 4; ++r)
                    xzb[(s + 1) & 1][rowq + r][w * 16 + c16] = xacc[r];
            }
            __syncthreads();

            // --- poll (R9 exact: wave 0, spread flags) ---
            if (w == 0) {
                const unsigned tgt = (unsigned)(s + 1);
                const unsigned int* fp = gflags + (size_t)(lane & 31) * 32;
                int iter = 0;
                for (;;) {
                    unsigned v;
                    asm volatile("global_load_dword %0, %1, off sc0 sc1\n\ts_waitcnt vmcnt(0)"
                                 : "=v"(v) : "v"(fp) : "memory");
                    if (__all((int)(v >= tgt))) break;
                    if (++iter > (1 << 18)) break;   // fail loud, never hang
                    __builtin_amdgcn_s_sleep(1);
                }
            }
            __syncthreads();
        }
    }
}

// ---------------- launch ----------------

extern "C" void kernel_launch(void* const* d_in, const int* in_sizes, int n_in,
                              void* d_out, int out_size, void* d_ws, size_t ws_size,
                              hipStream_t stream) {
    const float* x    = (const float*)d_in[0];   // [64][512][512]
    const float* Wx   = (const float*)d_in[1];   // [512][4096]
    const float* Wh   = (const float*)d_in[2];   // [1024][4096]
    const float* bias = (const float*)d_in[3];   // [4096]

    char* ws = (char*)d_ws;
    unsigned short* WxT   = (unsigned short*)(ws);                            // 4 MB
    unsigned short* WhT   = (unsigned short*)(ws + (4u << 20));               // 8 MB
    unsigned short* hbuf  = (unsigned short*)(ws + (12u << 20));              // 256 KB
    unsigned int*   flags = (unsigned int*)(ws + (12u << 20) + (256u << 10)); // 16 KB

    k_transpose_bf16<<<dim3(128, 16), dim3(32, 32), 0, stream>>>(Wx, WxT, 512, 4096);
    k_transpose_bf16<<<dim3(128, 32), dim3(32, 32), 0, stream>>>(Wh, WhT, 1024, 4096);
    k_init<<<160, 512, 0, stream>>>((unsigned int*)hbuf, flags);

    k_lstm<<<128, 512, 0, stream>>>(x, WxT, WhT, bias, hbuf, (float*)d_out, flags);
}

// Round 15
// 1652.442 us; speedup vs baseline: 2.2147x; 2.2147x over previous
//
#include <hip/hip_runtime.h>
#include <hip/hip_bf16.h>

// BasicLSTM: B=64, T=512, D=512, U=1024.  out = h_last [64][1024] f32.
// Round 15: producer/consumer specialization in ONE launch.
//  blocks 0-127 : R9 recurrence verbatim (4 m-groups x 32 z-blocks),
//                 xz read from a 64-step ring via sc0sc1, readiness via
//                 8 extra poll lanes. c in registers for all 512 steps.
//  blocks 128-255: xproj producers (8 col-slices x 16 t-interleave),
//                 running ahead, writing ring + flags via sc0sc1; pacing
//                 by consumer h-flags before ring-slot reuse.
// All polls capped (fail loud). No placement/scope assumptions beyond
// proven R9 (sc0sc1 = L3 coherent point).

#define T_STEPS 512
#define BATCH   64
#define DIM     512
#define UNITS   1024
#define ZCOLS   4096
#define MR      16
#define RING    64

typedef float        f32x4 __attribute__((ext_vector_type(4)));
typedef unsigned int u32x4 __attribute__((ext_vector_type(4)));

__device__ __forceinline__ f32x4 mfma16x16x32_bf16(u32x4 a, u32x4 b, f32x4 c) {
    asm("v_mfma_f32_16x16x32_bf16 %0, %1, %2, %0" : "+v"(c) : "v"(a), "v"(b));
    return c;
}

__device__ __forceinline__ unsigned short f2bf(float f) {
    union { float f; unsigned u; } v; v.f = f;
    unsigned r = v.u + 0x7fffu + ((v.u >> 16) & 1u);   // RNE
    return (unsigned short)(r >> 16);
}

__device__ __forceinline__ float fsigmoid(float x) { return 1.0f / (1.0f + __expf(-x)); }
__device__ __forceinline__ float ftanh(float x)    { return 1.0f - 2.0f / (__expf(2.0f * x) + 1.0f); }

__device__ __forceinline__ u32x4 pack8(const float* __restrict__ p) {
    float4 f0 = reinterpret_cast<const float4*>(p)[0];
    float4 f1 = reinterpret_cast<const float4*>(p)[1];
    u32x4 r;
    r.x = (unsigned)f2bf(f0.x) | ((unsigned)f2bf(f0.y) << 16);
    r.y = (unsigned)f2bf(f0.z) | ((unsigned)f2bf(f0.w) << 16);
    r.z = (unsigned)f2bf(f1.x) | ((unsigned)f2bf(f1.y) << 16);
    r.w = (unsigned)f2bf(f1.z) | ((unsigned)f2bf(f1.w) << 16);
    return r;
}

#define LD4(d, base) \
    asm volatile("global_load_dwordx4 %0, %1, off sc0 sc1" : "=v"(d) : "v"(base));
#define LDW(d, base) \
    asm volatile("global_load_dword %0, %1, off sc0 sc1\n\ts_waitcnt vmcnt(0)" \
                 : "=v"(d) : "v"(base) : "memory");
#define STW(base, v) \
    asm volatile("global_store_dword %0, %1, off sc0 sc1" :: "v"(base), "v"(v) : "memory");
#define WAITV0 \
    asm volatile("s_waitcnt vmcnt(0)" ::: "memory"); \
    __builtin_amdgcn_sched_barrier(0);

// ---------------- prep kernels ----------------

__global__ void k_transpose_bf16(const float* __restrict__ in, unsigned short* __restrict__ out,
                                 int K, int N) {
    __shared__ float tile[32][33];
    int n0 = blockIdx.x * 32, k0 = blockIdx.y * 32;
    int tx = threadIdx.x, ty = threadIdx.y;
    tile[ty][tx] = in[(size_t)(k0 + ty) * N + n0 + tx];
    __syncthreads();
    out[(size_t)(n0 + ty) * K + k0 + tx] = f2bf(tile[tx][ty]);
}

__global__ void k_init(unsigned int* __restrict__ hbuf_u32,
                       unsigned int* __restrict__ hflags,
                       unsigned int* __restrict__ xzflags) {
    int i = blockIdx.x * blockDim.x + threadIdx.x;           // 160*512 = 81920
    if (i < 65536) hbuf_u32[i] = 0u;                         // 2*64*1024 bf16
    else if (i < 65536 + 4096) hflags[i - 65536] = 0u;       // 128 * 32 u32
    else if (i < 65536 + 4096 + 512) xzflags[i - 69632] = 0u;// [64][8]
}

// ---------------- fused producer/consumer kernel ----------------
__global__ __launch_bounds__(512, 1) void k_fused(
        const float* __restrict__ x,             // [64][512][512] f32
        const unsigned short* __restrict__ WxT,  // [4096][512] bf16
        const unsigned short* __restrict__ WhT,  // [4096][1024] bf16
        const float* __restrict__ bias,          // [4096] f32
        unsigned short* hbuf,                    // [2][64][1024] bf16
        float* __restrict__ out,                 // [64][1024] f32
        unsigned int* hflags,                    // [128] spaced 32 u32
        unsigned int* xzflags,                   // [RING][8] packed u32
        float* __restrict__ xzring) {            // [RING][64][4096] f32
    __shared__ __align__(16) char smem[65536];
    const int tid  = threadIdx.x;
    const int lane = tid & 63;
    const int w    = tid >> 6;

    if (blockIdx.x < 128) {
        // ================= CONSUMER: R9 recurrence =================
        unsigned short* hs = (unsigned short*)smem;          // 32 KB swizzled
        float* zb = (float*)(smem + 32768);                  // [2][16][132]
        const int ct  = w & 3;
        const int kh  = w >> 2;
        const int mg  = blockIdx.x >> 5;
        const int zbk = blockIdx.x & 31;
        const int r0  = mg * MR;
        const int u0  = zbk * 32;
        const int c16 = lane & 15;
        const int kl  = (lane >> 4) * 8;
        const int klb = (lane >> 4) * 16;

        u32x4 breg[2][16];
        #pragma unroll
        for (int n = 0; n < 2; ++n) {
            const unsigned short* wp =
                WhT + ((size_t)(ct * UNITS + u0 + n * 16 + c16)) * UNITS + kh * 512 + kl;
            #pragma unroll
            for (int kk = 0; kk < 16; ++kk) {
                breg[n][kk] = *reinterpret_cast<const u32x4*>(wp + kk * 32);
                asm volatile("" : "+v"(breg[n][kk]));
            }
        }

        const int ri = tid >> 5;
        const int ui = tid & 31;
        float creg = 0.0f;

        unsigned int* const myflag = hflags + (size_t)blockIdx.x * 32;
        const unsigned int* const gflags = hflags + (size_t)mg * 32 * 32;

        // prologue: wait xz(0) ready (slot 0, all 8 col-slices == 1)
        if (w == 0) {
            const unsigned int* fp = xzflags + (lane & 7);
            int iter = 0;
            for (;;) {
                unsigned v; LDW(v, fp)
                bool ok = (lane < 8) ? (v == 1u) : true;
                if (__all((int)ok)) break;
                if (++iter > (1 << 20)) break;
                __builtin_amdgcn_s_sleep(1);
            }
        }
        __syncthreads();

        for (int s = 0; s < T_STEPS; ++s) {
            const unsigned short* hrd = hbuf + (size_t)(s & 1) * (BATCH * UNITS);

            // --- stage group h(s) -> swizzled LDS (R9 exact) ---
            {
                u32x4 sv[4];
                #pragma unroll
                for (int j = 0; j < 4; ++j) {
                    int i = tid + j * 512;
                    int row = i >> 7, kc = i & 127;
                    const unsigned short* src = hrd + (size_t)(r0 + row) * UNITS + kc * 8;
                    LD4(sv[j], src)
                }
                WAITV0
                #pragma unroll
                for (int j = 0; j < 4; ++j) {
                    int i = tid + j * 512;
                    int row = i >> 7, kc = i & 127;
                    int lb = (row * 2048 + kc * 16) ^ ((row & 7) << 4);
                    *reinterpret_cast<u32x4*>(reinterpret_cast<char*>(hs) + lb) = sv[j];
                }
            }
            __syncthreads();

            // xz loads from ring (sc0sc1; drain after MFMA)
            float xv0, xv1, xv2, xv3;
            {
                const float* xp = xzring + ((size_t)(s & (RING - 1)) * BATCH + r0 + ri) * ZCOLS
                                  + u0 + ui;
                asm volatile("global_load_dword %0, %1, off sc0 sc1" : "=v"(xv0) : "v"(xp));
                asm volatile("global_load_dword %0, %1, off sc0 sc1" : "=v"(xv1) : "v"(xp + UNITS));
                asm volatile("global_load_dword %0, %1, off sc0 sc1" : "=v"(xv2) : "v"(xp + 2 * UNITS));
                asm volatile("global_load_dword %0, %1, off sc0 sc1" : "=v"(xv3) : "v"(xp + 3 * UNITS));
            }

            // --- h @ Wh MFMA (R9 exact) ---
            f32x4 acc0 = {0, 0, 0, 0}, acc1 = {0, 0, 0, 0};
            asm volatile("s_nop 1" : "+v"(acc0), "+v"(acc1));
            const char* abase = reinterpret_cast<const char*>(hs);
            const int axor = (c16 & 7) << 4;
            #pragma unroll
            for (int kk = 0; kk < 16; ++kk) {
                int lb = (c16 * 2048 + kh * 1024 + kk * 64 + klb) ^ axor;
                u32x4 a = *reinterpret_cast<const u32x4*>(abase + lb);
                acc0 = mfma16x16x32_bf16(a, breg[0][kk], acc0);
                acc1 = mfma16x16x32_bf16(a, breg[1][kk], acc1);
            }
            asm volatile("s_nop 7\n\ts_nop 7" : "+v"(acc0), "+v"(acc1));
            {
                const int rowq = (lane >> 4) * 4;
                #pragma unroll
                for (int r = 0; r < 4; ++r) {
                    zb[((kh * 16 + rowq + r)) * 132 + ct * 32 + c16]      = acc0[r];
                    zb[((kh * 16 + rowq + r)) * 132 + ct * 32 + 16 + c16] = acc1[r];
                }
            }
            __syncthreads();
            WAITV0   // xz loads complete

            // --- gates (bias folded into ring by producers) ---
            {
                float zi = zb[ri * 132 + ui]      + zb[(16 + ri) * 132 + ui]      + xv0;
                float zf = zb[ri * 132 + 32 + ui] + zb[(16 + ri) * 132 + 32 + ui] + xv1;
                float zg = zb[ri * 132 + 64 + ui] + zb[(16 + ri) * 132 + 64 + ui] + xv2;
                float zo = zb[ri * 132 + 96 + ui] + zb[(16 + ri) * 132 + 96 + ui] + xv3;
                float ig = fsigmoid(zi), fg = fsigmoid(zf), gg = ftanh(zg), og = fsigmoid(zo);
                creg = fg * creg + ig * gg;
                float hn = og * ftanh(creg);
                unsigned hv = f2bf(hn);
                unsigned short* hwp = hbuf + (size_t)((s + 1) & 1) * (BATCH * UNITS)
                                      + (size_t)(r0 + ri) * UNITS + u0 + ui;
                asm volatile("global_store_short %0, %1, off sc0 sc1" :: "v"(hwp), "v"(hv) : "memory");
                if (s == T_STEPS - 1) out[(size_t)(r0 + ri) * UNITS + u0 + ui] = hn;
            }

            if (s < T_STEPS - 1) {
                WAITV0                        // own h stores acked (L3)
                __syncthreads();              // whole block drained
                if (tid == 0) {
                    STW(myflag, (unsigned)(s + 1))
                    asm volatile("s_waitcnt vmcnt(0)" ::: "memory");
                }
                if (w == 0) {                 // combined h + xz poll
                    const unsigned tgtH = (unsigned)(s + 1);
                    const unsigned tgtX = (unsigned)(s + 2);
                    const unsigned int* fp = (lane < 32)
                        ? gflags + (size_t)lane * 32
                        : xzflags + (size_t)((s + 1) & (RING - 1)) * 8 + (lane & 7);
                    int iter = 0;
                    for (;;) {
                        unsigned v; LDW(v, fp)
                        bool ok = (lane < 32) ? (v >= tgtH)
                                  : ((lane < 40) ? (v == tgtX) : true);
                        if (__all((int)ok)) break;
                        if (++iter > (1 << 20)) break;
                        __builtin_amdgcn_s_sleep(1);
                    }
                }
                __syncthreads();
            }
        }
    } else {
        // ================= PRODUCER: xproj into ring =================
        unsigned short* as_ = (unsigned short*)smem;         // 64 KB swizzled
        const int p   = blockIdx.x - 128;
        const int bx  = p & 7;               // 512-col slice
        const int jt  = p >> 3;              // t offset 0..15
        const int n0  = bx * 512 + w * 64;
        const int r16 = lane & 15;
        const int kl  = (lane >> 4) * 8;

        for (int k2 = 0; k2 < T_STEPS / 16; ++k2) {
            const int t = jt + 16 * k2;

            // pacing: slot reuse safe once all consumers passed t-RING
            if (t >= RING) {
                if (w == 0) {
                    const unsigned need = (unsigned)(t - RING + 1);
                    int iter = 0;
                    for (;;) {
                        unsigned v0, v1;
                        LDW(v0, hflags + (size_t)lane * 32)
                        LDW(v1, hflags + (size_t)(lane + 64) * 32)
                        if (__all((int)(v0 >= need && v1 >= need))) break;
                        if (++iter > (1 << 20)) break;
                        __builtin_amdgcn_s_sleep(1);
                    }
                }
                __syncthreads();
            }

            // stage x(:, t, :) -> packed bf16 swizzled LDS
            for (int i = tid; i < 4096; i += 512) {
                int row = i >> 6, kc8 = i & 63;
                u32x4 v = pack8(x + ((size_t)row * T_STEPS + t) * DIM + kc8 * 8);
                int lb = (row * 1024 + kc8 * 16) ^ ((row & 7) << 4);
                *reinterpret_cast<u32x4*>(reinterpret_cast<char*>(as_) + lb) = v;
            }
            __syncthreads();

            const unsigned short* bp = WxT + (size_t)(n0 + r16) * DIM + kl;
            f32x4 acc[4][4] = {};
            asm volatile("s_nop 1" : "+v"(acc[0][0]), "+v"(acc[1][1]), "+v"(acc[2][2]), "+v"(acc[3][3]));
            #pragma unroll 2
            for (int kk = 0; kk < 16; ++kk) {
                u32x4 b0 = *reinterpret_cast<const u32x4*>(bp + kk * 32);
                u32x4 b1 = *reinterpret_cast<const u32x4*>(bp + 16 * DIM + kk * 32);
                u32x4 b2 = *reinterpret_cast<const u32x4*>(bp + 32 * DIM + kk * 32);
                u32x4 b3 = *reinterpret_cast<const u32x4*>(bp + 48 * DIM + kk * 32);
                u32x4 a[4];
                #pragma unroll
                for (int mt = 0; mt < 4; ++mt) {
                    int row = mt * 16 + r16;
                    int lb = (row * 1024 + (kk * 32 + kl) * 2) ^ ((row & 7) << 4);
                    a[mt] = *reinterpret_cast<const u32x4*>(reinterpret_cast<const char*>(as_) + lb);
                }
                #pragma unroll
                for (int mt = 0; mt < 4; ++mt) {
                    acc[mt][0] = mfma16x16x32_bf16(a[mt], b0, acc[mt][0]);
                    acc[mt][1] = mfma16x16x32_bf16(a[mt], b1, acc[mt][1]);
                    acc[mt][2] = mfma16x16x32_bf16(a[mt], b2, acc[mt][2]);
                    acc[mt][3] = mfma16x16x32_bf16(a[mt], b3, acc[mt][3]);
                }
            }
            asm volatile("s_nop 7\n\ts_nop 7" : "+v"(acc[0][0]), "+v"(acc[1][1]), "+v"(acc[2][2]), "+v"(acc[3][3]));

            // write xz (+bias) to ring slot via sc0sc1
            {
                float* ringb = xzring + (size_t)(t & (RING - 1)) * BATCH * ZCOLS;
                const int rowq = (lane >> 4) * 4;
                #pragma unroll
                for (int nt = 0; nt < 4; ++nt) {
                    const int col = n0 + nt * 16 + r16;
                    const float bv = bias[col];
                    #pragma unroll
                    for (int mt = 0; mt < 4; ++mt) {
                        #pragma unroll
                        for (int r = 0; r < 4; ++r) {
                            float val = acc[mt][nt][r] + bv;
                            float* dst = ringb + (size_t)(mt * 16 + rowq + r) * ZCOLS + col;
                            asm volatile("global_store_dword %0, %1, off sc0 sc1"
                                         :: "v"(dst), "v"(val) : "memory");
                        }
                    }
                }
            }
            WAITV0
            __syncthreads();                 // whole block's slice in L3
            if (tid == 0) STW(xzflags + (size_t)(t & (RING - 1)) * 8 + bx, (unsigned)(t + 1))
            __syncthreads();
        }
    }
}

// ---------------- launch ----------------

extern "C" void kernel_launch(void* const* d_in, const int* in_sizes, int n_in,
                              void* d_out, int out_size, void* d_ws, size_t ws_size,
                              hipStream_t stream) {
    const float* x    = (const float*)d_in[0];   // [64][512][512]
    const float* Wx   = (const float*)d_in[1];   // [512][4096]
    const float* Wh   = (const float*)d_in[2];   // [1024][4096]
    const float* bias = (const float*)d_in[3];   // [4096]

    char* ws = (char*)d_ws;
    unsigned short* WxT     = (unsigned short*)(ws);                            // 4 MB
    unsigned short* WhT     = (unsigned short*)(ws + (4u << 20));               // 8 MB
    unsigned short* hbuf    = (unsigned short*)(ws + (12u << 20));              // 256 KB
    unsigned int*   hflags  = (unsigned int*)(ws + (12u << 20) + (256u << 10)); // 16 KB
    unsigned int*   xzflags = (unsigned int*)(ws + (12u << 20) + (272u << 10)); // 2 KB
    float*          xzring  = (float*)(ws + (13u << 20));                       // 64 MB

    k_transpose_bf16<<<dim3(128, 16), dim3(32, 32), 0, stream>>>(Wx, WxT, 512, 4096);
    k_transpose_bf16<<<dim3(128, 32), dim3(32, 32), 0, stream>>>(Wh, WhT, 1024, 4096);
    k_init<<<160, 512, 0, stream>>>((unsigned int*)hbuf, hflags, xzflags);

    k_fused<<<256, 512, 0, stream>>>(x, WxT, WhT, bias, hbuf, (float*)d_out,
                                     hflags, xzflags, xzring);
}